// Round 10
// baseline (95.519 us; speedup 1.0000x reference)
//
#include <hip/hip_runtime.h>

#define NB 8
#define NS 4
#define NN 8192
#define NM 50
#define K10 10
#define THREADS 256
#define COST_THRESH 50.0f
#define LOSS_BLOCKS 256
#define NBUCK 1024
#define CAP 256
#define TOTAL (NB * NS * NN)

__device__ __forceinline__ bool lexless(float d1, int i1, float d2, int i2) {
  // matches jax.lax.top_k ordering on -dist: (dist asc, index asc)
  return (d1 < d2) || (d1 == d2 && i1 < i2);
}

__global__ void __launch_bounds__(256) init_kernel(int* __restrict__ assign,
                                                   float* __restrict__ acc,
                                                   int* __restrict__ bs_unm) {
  int i = blockIdx.x * blockDim.x + threadIdx.x;
  for (int j = i; j < TOTAL; j += gridDim.x * blockDim.x) assign[j] = -1;
  if (i == 0) acc[0] = 0.0f;  // per_gt_sum
  if (i >= 64 && i < 64 + NB * NS) bs_unm[i - 64] = 0;
}

// R3-exact: one block per (b, s, m), LDS-resident d^2, histogram-select.
__global__ void __launch_bounds__(256) topk_kernel(
    const float* __restrict__ pred_boxes, const float* __restrict__ pred_scores,
    const float* __restrict__ gt_boxes, const int* __restrict__ n_gt,
    int* __restrict__ assign, float* __restrict__ per_gt_sum,
    int* __restrict__ bs_unm) {
  const int blk = blockIdx.x;      // b*NS*NM + s*NM + m
  const int m = blk % NM;
  const int bs = blk / NM;
  const int b = bs / NS;
  const int t = threadIdx.x;

  __shared__ float sd2[NN];        // 32 KB: d^2 per pred
  __shared__ int shist[NBUCK];     // 4 KB
  __shared__ float scd[CAP];       // candidate d^2 -> later sqrt'd dist
  __shared__ int sci[CAP];         // candidate idx
  __shared__ float sred[16];       // min/max staging
  __shared__ float sbb[2];         // bmin, scale
  __shared__ int scnt;
  __shared__ int sbucket;
  __shared__ float soutd[K10];
  __shared__ int souti[K10];

  for (int i = t; i < NBUCK; i += THREADS) shist[i] = 0;
  if (t == 0) { scnt = 0; sbucket = NBUCK - 2; }

  const float gx = gt_boxes[(b * NM + m) * 7 + 0];
  const float gy = gt_boxes[(b * NM + m) * 7 + 1];
  const float gz = gt_boxes[(b * NM + m) * 7 + 2];
  const bool valid = (m < n_gt[b]);

  // P1: d^2 for all preds -> LDS; track min/max
  const float* pb = pred_boxes + (size_t)bs * NN * 7;
  float lmin = INFINITY, lmax = 0.0f;
#pragma unroll
  for (int k = 0; k < NN / THREADS; k++) {
    int n = t + k * THREADS;
    float dx = pb[n * 7 + 0] - gx;
    float dy = pb[n * 7 + 1] - gy;
    float dz = pb[n * 7 + 2] - gz;
    float d2 = dx * dx + dy * dy + dz * dz;
    sd2[n] = d2;
    lmin = fminf(lmin, d2);
    lmax = fmaxf(lmax, d2);
  }
#pragma unroll
  for (int off = 32; off >= 1; off >>= 1) {
    lmin = fminf(lmin, __shfl_down(lmin, off));
    lmax = fmaxf(lmax, __shfl_down(lmax, off));
  }
  int wave = t >> 6;
  if ((t & 63) == 0) { sred[wave] = lmin; sred[8 + wave] = lmax; }
  __syncthreads();
  if (t == 0) {
    float bmin = fminf(fminf(sred[0], sred[1]), fminf(sred[2], sred[3]));
    float bmax = fmaxf(fmaxf(sred[8], sred[9]), fmaxf(sred[10], sred[11]));
    sbb[0] = bmin;
    sbb[1] = (float)NBUCK / fmaxf(bmax - bmin, 1e-30f);
  }
  __syncthreads();
  const float bmin = sbb[0], scale = sbb[1];

  // P2: histogram on d^2
#pragma unroll
  for (int k = 0; k < NN / THREADS; k++) {
    int n = t + k * THREADS;
    int bidx = (int)((sd2[n] - bmin) * scale);
    bidx = min(NBUCK - 1, max(0, bidx));
    atomicAdd(&shist[bidx], 1);
  }
  __syncthreads();

  // P3: first bucket j with cumulative count >= 10 (single wave)
  if (t < 64) {
    int lsum = 0;
    for (int i = 0; i < NBUCK / 64; i++) lsum += shist[t * (NBUCK / 64) + i];
    int incl = lsum;
#pragma unroll
    for (int off = 1; off < 64; off <<= 1) {
      int v = __shfl_up(incl, off);
      if (t >= off) incl += v;
    }
    int excl = incl - lsum;
    if (excl < K10 && incl >= K10) {
      int c = excl;
      for (int i = 0; i < NBUCK / 64; i++) {
        c += shist[t * (NBUCK / 64) + i];
        if (c >= K10) { sbucket = t * (NBUCK / 64) + i; break; }
      }
    }
  }
  __syncthreads();
  // hi-edge of bucket j+1 plus half-bin margin (covers edge rounding + sqrt-ties)
  const float bound = bmin + ((float)(sbucket + 2) + 0.5f) / scale;

  // P4: collect candidates below bound (superset of exact top-10)
#pragma unroll
  for (int k = 0; k < NN / THREADS; k++) {
    int n = t + k * THREADS;
    float d2 = sd2[n];
    if (d2 < bound) {
      int p = atomicAdd(&scnt, 1);
      if (p < CAP) { scd[p] = d2; sci[p] = n; }
    }
  }
  __syncthreads();
  const int K = min(scnt, CAP);

  // P5: sqrt candidates (matches reference dist exactly), exact rank by (d, idx)
  for (int c = t; c < K; c += THREADS) scd[c] = sqrtf(scd[c]);
  __syncthreads();
  for (int c = t; c < K; c += THREADS) {
    float dc = scd[c];
    int ic = sci[c];
    int rank = 0;
    for (int o = 0; o < K; o++) rank += lexless(scd[o], sci[o], dc, ic) ? 1 : 0;
    if (rank < K10) { soutd[rank] = dc; souti[rank] = ic; }
  }
  __syncthreads();

  if (t == 0) {
    bool matched = false;
#pragma unroll
    for (int k = 0; k < K10; k++) {
      if (valid && soutd[k] < COST_THRESH) {
        matched = true;
        atomicMax(&assign[(size_t)bs * NN + souti[k]], m);
      }
    }
    if (valid && !matched) {
      const float* ps = pred_scores + (size_t)bs * NN;
      float a = 0.0f;
#pragma unroll
      for (int k = 0; k < 5; k++) a += expf(-0.5f * soutd[k]) * (1.0f - ps[souti[k]]);
      atomicAdd(per_gt_sum, a * 0.2f);
      atomicOr(&bs_unm[bs], 1);
    }
  }
}

// Two-stage reduction: each block writes one partial row (no global atomics).
__global__ void __launch_bounds__(256) loss_kernel(
    const float* __restrict__ pred_boxes, const float* __restrict__ pred_scores,
    const float* __restrict__ gt_boxes, const int* __restrict__ assign,
    float* __restrict__ partials) {
  int tid = blockIdx.x * blockDim.x + threadIdx.x;
  float lc = 0.0f, spp = 0.0f, spn = 0.0f, np = 0.0f;
  for (int i = tid; i < TOTAL; i += gridDim.x * blockDim.x) {
    int a = assign[i];
    float x = pred_scores[i];
    if (a >= 0) {
      np += 1.0f;
      int b = i / (NS * NN);
      const float* pbp = &pred_boxes[(size_t)i * 7];
      const float* gbp = &gt_boxes[(b * NM + a) * 7];
#pragma unroll
      for (int c = 0; c < 3; c++) {
        float diff = pbp[c] - gbp[c];
        float ad = fabsf(diff);
        lc += (ad < 1.0f) ? 0.5f * ad * ad : (ad - 0.5f);
      }
      spp += log1pf(expf(-fabsf(x))) + fmaxf(-x, 0.0f);  // softplus(-x)
    } else {
      spn += log1pf(expf(-fabsf(x))) + fmaxf(x, 0.0f);   // softplus(x)
    }
  }
#pragma unroll
  for (int off = 32; off >= 1; off >>= 1) {
    lc += __shfl_down(lc, off);
    spp += __shfl_down(spp, off);
    spn += __shfl_down(spn, off);
    np += __shfl_down(np, off);
  }
  __shared__ float red[4][4];
  int wave = threadIdx.x >> 6;
  if ((threadIdx.x & 63) == 0) {
    red[wave][0] = lc; red[wave][1] = spp; red[wave][2] = spn; red[wave][3] = np;
  }
  __syncthreads();
  if (threadIdx.x == 0) {
    float o0 = 0, o1 = 0, o2 = 0, o3 = 0;
#pragma unroll
    for (int w = 0; w < 4; w++) { o0 += red[w][0]; o1 += red[w][1]; o2 += red[w][2]; o3 += red[w][3]; }
    float* p = &partials[(size_t)blockIdx.x * 8];
    p[0] = o0; p[1] = o1; p[2] = o2; p[3] = o3;
  }
}

__global__ void __launch_bounds__(256) final_kernel(
    const float* __restrict__ partials, const float* __restrict__ acc,
    const int* __restrict__ bs_unm,
    const float* __restrict__ wc, const float* __restrict__ wo,
    const float* __restrict__ wu, float* __restrict__ out) {
  const int t = threadIdx.x;
  const float* p = &partials[(size_t)t * 8];
  float lc = p[0], spp = p[1], spn = p[2], np = p[3];
#pragma unroll
  for (int off = 32; off >= 1; off >>= 1) {
    lc += __shfl_down(lc, off);
    spp += __shfl_down(spp, off);
    spn += __shfl_down(spn, off);
    np += __shfl_down(np, off);
  }
  __shared__ float red[4][4];
  int wave = t >> 6;
  if ((t & 63) == 0) {
    red[wave][0] = lc; red[wave][1] = spp; red[wave][2] = spn; red[wave][3] = np;
  }
  __syncthreads();
  if (t == 0) {
    float o0 = 0, o1 = 0, o2 = 0, o3 = 0;
#pragma unroll
    for (int w = 0; w < 4; w++) { o0 += red[w][0]; o1 += red[w][1]; o2 += red[w][2]; o3 += red[w][3]; }
    int ne = 0;
    for (int i = 0; i < NB * NS; i++) ne += bs_unm[i];
    float n_pos = o3;
    float loss_center = o0 / fmaxf(n_pos * 3.0f, 1.0f);
    float n_neg = (float)TOTAL - n_pos;
    float pw = fminf(10.0f, n_neg / fmaxf(n_pos, 1.0f));
    float loss_obj = (pw * o1 + o2) / (float)TOTAL;
    float loss_unm = acc[0] / fmaxf((float)ne, 1.0f);
    out[0] = loss_center * wc[0] + loss_obj * wo[0] + loss_unm * wu[0];
  }
}

extern "C" void kernel_launch(void* const* d_in, const int* in_sizes, int n_in,
                              void* d_out, int out_size, void* d_ws, size_t ws_size,
                              hipStream_t stream) {
  const float* pred_boxes = (const float*)d_in[0];
  // d_in[1] = pred_classes (unused), d_in[4] = gt_classes (unused), d_in[9] = epoch (unused)
  const float* pred_scores = (const float*)d_in[2];
  const float* gt_boxes = (const float*)d_in[3];
  const int* n_gt = (const int*)d_in[5];
  const float* wc = (const float*)d_in[6];
  const float* wo = (const float*)d_in[7];
  const float* wu = (const float*)d_in[8];
  float* out = (float*)d_out;

  char* ws = (char*)d_ws;
  int* assign = (int*)ws;                           // TOTAL ints (1 MB)
  float* acc = (float*)(ws + (size_t)TOTAL * 4);    // acc[0] = per_gt_sum
  int* bs_unm = (int*)((char*)acc + 256);           // NB*NS ints
  float* partials = (float*)((char*)bs_unm + 256);  // LOSS_BLOCKS * 8 floats
  // dummy region for probe runs 2-3 (atomicMax idempotent; sums unused)
  char* dummy = ws + 2 * 1024 * 1024;
  int* dummy_assign = (int*)dummy;                  // 1 MB
  float* dummy_acc = (float*)(dummy + (size_t)TOTAL * 4);
  int* dummy_bs = (int*)((char*)dummy_acc + 256);

  init_kernel<<<256, 256, 0, stream>>>(assign, acc, bs_unm);
  // run 1: real
  topk_kernel<<<NB * NS * NM, THREADS, 0, stream>>>(pred_boxes, pred_scores, gt_boxes,
                                                    n_gt, assign, &acc[0], bs_unm);
  // runs 2-3: timing probe into dummy buffers (no effect on output)
  topk_kernel<<<NB * NS * NM, THREADS, 0, stream>>>(pred_boxes, pred_scores, gt_boxes,
                                                    n_gt, dummy_assign, &dummy_acc[0], dummy_bs);
  topk_kernel<<<NB * NS * NM, THREADS, 0, stream>>>(pred_boxes, pred_scores, gt_boxes,
                                                    n_gt, dummy_assign, &dummy_acc[0], dummy_bs);
  loss_kernel<<<LOSS_BLOCKS, 256, 0, stream>>>(pred_boxes, pred_scores, gt_boxes, assign, partials);
  final_kernel<<<1, 256, 0, stream>>>(partials, acc, bs_unm, wc, wo, wu, out);
}

// Round 11
// 47.491 us; speedup vs baseline: 2.0113x; 2.0113x over previous
//
#include <hip/hip_runtime.h>

#define NB 8
#define NS 4
#define NN 8192
#define NM 50
#define K10 10
#define COST_THRESH 50.0f
#define TOTAL (NB * NS * NN)
#define TKT 256            // topk threads (4 waves)
#define TKE 32             // elems per thread
#define CAP 2048           // candidate storage
#define ACCEPT 256         // acceptance upper bound for count
#define LFT 512            // loss_final threads
#define SUBS 4             // sub-blocks per bs
#define LF_BLOCKS (NB * NS * SUBS)   // 128

__device__ __forceinline__ bool lexless(float d1, int i1, float d2, int i2) {
  // matches jax.lax.top_k ordering on -dist: (dist asc, index asc)
  return (d1 < d2) || (d1 == d2 && i1 < i2);
}

// Pack pred xyz into SoA streams (bit-exact) + reset ticket counter.
__global__ void __launch_bounds__(256) prep_kernel(
    const float* __restrict__ pred_boxes, float* __restrict__ packed,
    int* __restrict__ done) {
  int i = blockIdx.x * blockDim.x + threadIdx.x;
  for (int j = i; j < TOTAL; j += gridDim.x * blockDim.x) {
    packed[j] = pred_boxes[j * 7 + 0];
    packed[TOTAL + j] = pred_boxes[j * 7 + 1];
    packed[2 * TOTAL + j] = pred_boxes[j * 7 + 2];
  }
  if (i == 0) *done = 0;
}

// One block per (b, s, m): raw top-10 nearest preds by (dist, idx), written
// compactly to outd/outi. d^2 register-resident; bound found by growth-first
// uniform counting (no LDS atomics in selection, few barrier iterations).
__global__ void __launch_bounds__(TKT, 4) topk_kernel(
    const float* __restrict__ packed, const float* __restrict__ gt_boxes,
    float* __restrict__ outd, int* __restrict__ outi) {
  const int blk = blockIdx.x;      // bs*NM + m
  const int m = blk % NM;
  const int bs = blk / NM;
  const int b = bs / NS;
  const int t = threadIdx.x;
  const int wave = t >> 6;
  const int lane = t & 63;

  __shared__ float scd[CAP];       // 8 KB
  __shared__ int sci[CAP];         // 8 KB
  __shared__ float sred[2][4];
  __shared__ int scount[2][4];
  __shared__ int scnt;
  __shared__ float soutd[K10];
  __shared__ int souti[K10];

  if (t == 0) scnt = 0;

  const float gx = gt_boxes[(b * NM + m) * 7 + 0];
  const float gy = gt_boxes[(b * NM + m) * 7 + 1];
  const float gz = gt_boxes[(b * NM + m) * 7 + 2];

  const float4* px4 = (const float4*)(packed + (size_t)bs * NN);
  const float4* py4 = (const float4*)(packed + TOTAL + (size_t)bs * NN);
  const float4* pz4 = (const float4*)(packed + 2 * TOTAL + (size_t)bs * NN);

  // P1: d^2 into registers (32/thread); block min/max
  float d2r[TKE];
  float lmin = INFINITY, lmax = 0.0f;
#pragma unroll
  for (int c = 0; c < TKE / 4; c++) {
    float4 vx = px4[c * TKT + t];
    float4 vy = py4[c * TKT + t];
    float4 vz = pz4[c * TKT + t];
    float dx, dy, dz;
    dx = vx.x - gx; dy = vy.x - gy; dz = vz.x - gz; d2r[c * 4 + 0] = dx * dx + dy * dy + dz * dz;
    dx = vx.y - gx; dy = vy.y - gy; dz = vz.y - gz; d2r[c * 4 + 1] = dx * dx + dy * dy + dz * dz;
    dx = vx.z - gx; dy = vy.z - gy; dz = vz.z - gz; d2r[c * 4 + 2] = dx * dx + dy * dy + dz * dz;
    dx = vx.w - gx; dy = vy.w - gy; dz = vz.w - gz; d2r[c * 4 + 3] = dx * dx + dy * dy + dz * dz;
#pragma unroll
    for (int j = 0; j < 4; j++) {
      lmin = fminf(lmin, d2r[c * 4 + j]);
      lmax = fmaxf(lmax, d2r[c * 4 + j]);
    }
  }
#pragma unroll
  for (int off = 32; off >= 1; off >>= 1) {
    lmin = fminf(lmin, __shfl_down(lmin, off));
    lmax = fmaxf(lmax, __shfl_down(lmax, off));
  }
  if (lane == 0) { sred[0][wave] = lmin; sred[1][wave] = lmax; }
  __syncthreads();
  const float bmin = fminf(fminf(sred[0][0], sred[0][1]), fminf(sred[0][2], sred[0][3]));
  const float bmax = fmaxf(fmaxf(sred[1][0], sred[1][1]), fmaxf(sred[1][2], sred[1][3]));

  // P2: growth-first bound search; invariant: count(hi) >= 10, count(lo) < 10.
  float lo = bmin;
  float hi = bmax * 1.000001f + 1e-30f;
  float g = fmaxf(bmin * 4.0f, 1e-37f);
  bool have = false;   // found some hi' < bmax with count >= 10
  int buf = 0;
  for (int it = 0; it < 24; it++) {
    float probe = have ? 0.5f * (lo + hi) : fminf(g, hi);
    int c = 0;
#pragma unroll
    for (int e = 0; e < TKE; e++) c += (d2r[e] < probe) ? 1 : 0;
#pragma unroll
    for (int off = 32; off >= 1; off >>= 1) c += __shfl_down(c, off);
    if (lane == 0) scount[buf][wave] = c;
    __syncthreads();
    int C = scount[buf][0] + scount[buf][1] + scount[buf][2] + scount[buf][3];
    buf ^= 1;
    if (C >= K10) {
      hi = probe; have = true;
      if (C <= ACCEPT) break;
    } else {
      lo = probe;
      if (!have) { g *= 4.0f; if (g >= hi) have = true; }
    }
    if (have && !(hi > lo + fmaxf(lo, 1e-30f) * 1e-7f)) break;  // collapsed
  }
  const float bound = hi;

  // P3: collect candidates (wave-aggregated; 1 LDS atomic per wave per e)
#pragma unroll
  for (int e = 0; e < TKE; e++) {
    int n = ((e >> 2) * TKT + t) * 4 + (e & 3);   // matches d2r layout
    bool p = d2r[e] < bound;
    unsigned long long mask = __ballot(p);
    if (mask) {
      int leader = __ffsll((long long)mask) - 1;
      int cnt = __popcll(mask);
      int base = 0;
      if (lane == leader) base = atomicAdd(&scnt, cnt);
      base = __shfl(base, leader);
      int pos = base + __popcll(mask & ((1ull << lane) - 1ull));
      if (p && pos < CAP) { scd[pos] = d2r[e]; sci[pos] = n; }
    }
  }
  __syncthreads();
  const int K = min(scnt, CAP);

  // P4: sqrt (reference-exact dists), exact rank by (d, idx)
  for (int c = t; c < K; c += TKT) scd[c] = sqrtf(scd[c]);
  __syncthreads();
  for (int c = t; c < K; c += TKT) {
    float dc = scd[c];
    int ic = sci[c];
    int rank = 0;
    for (int o = 0; o < K; o++) rank += lexless(scd[o], sci[o], dc, ic) ? 1 : 0;
    if (rank < K10) { soutd[rank] = dc; souti[rank] = ic; }
  }
  __syncthreads();

  if (t < K10) {
    outd[blk * K10 + t] = soutd[t];
    outi[blk * K10 + t] = souti[t];
  }
}

// Fused: rebuild assign in LDS from compact top-10 lists, compute all loss
// partial sums, ticket-reduce, final combine. One bs per SUBS blocks.
__global__ void __launch_bounds__(LFT) loss_final_kernel(
    const float* __restrict__ pred_boxes, const float* __restrict__ pred_scores,
    const float* __restrict__ gt_boxes, const int* __restrict__ n_gt,
    const float* __restrict__ outd, const int* __restrict__ outi,
    float* __restrict__ partials, int* __restrict__ done,
    const float* __restrict__ wc, const float* __restrict__ wo,
    const float* __restrict__ wu, float* __restrict__ out) {
  const int blk = blockIdx.x;
  const int bs = blk / SUBS;
  const int sub = blk % SUBS;
  const int b = bs / NS;
  const int t = threadIdx.x;
  const int wave = t >> 6;

  __shared__ int lassign[NN];      // 32 KB
  __shared__ int matched[NM];
  __shared__ float spg;
  __shared__ int sunm;
  __shared__ float red[8][4];
  __shared__ float red2[2][8];
  __shared__ int s_last;

  for (int i = t; i < NN; i += LFT) lassign[i] = -1;
  if (t < NM) matched[t] = 0;
  if (t == 0) { spg = 0.0f; sunm = 0; }
  const int ngt = n_gt[b];
  __syncthreads();

  // scatter picks into LDS assign; mark matched gts
  if (t < NM * K10) {
    int m = t / K10, k = t % K10;
    if (m < ngt) {
      float d = outd[(bs * NM + m) * K10 + k];
      if (d < COST_THRESH) {
        atomicMax(&lassign[outi[(bs * NM + m) * K10 + k]], m);
        atomicOr(&matched[m], 1);
      }
    }
  }
  __syncthreads();

  // unmatched-gt term (sub 0 only, once per bs)
  if (sub == 0 && t < NM && t < ngt && matched[t] == 0) {
    float a = 0.0f;
#pragma unroll
    for (int k = 0; k < 5; k++) {
      float d = outd[(bs * NM + t) * K10 + k];
      float sc = pred_scores[(size_t)bs * NN + outi[(bs * NM + t) * K10 + k]];
      a += expf(-0.5f * d) * (1.0f - sc);
    }
    atomicAdd(&spg, a * 0.2f);
    atomicOr(&sunm, 1);
  }

  // main loss loop over this sub-block's pred range
  float lc = 0.0f, spp = 0.0f, spn = 0.0f, np = 0.0f;
  const int base = sub * (NN / SUBS);
#pragma unroll
  for (int j = 0; j < NN / SUBS / LFT; j++) {   // 4 iters
    int i = base + t + j * LFT;
    int a = lassign[i];
    float x = pred_scores[(size_t)bs * NN + i];
    if (a >= 0) {
      np += 1.0f;
#pragma unroll
      for (int c = 0; c < 3; c++) {
        float diff = pred_boxes[((size_t)bs * NN + i) * 7 + c] - gt_boxes[(b * NM + a) * 7 + c];
        float ad = fabsf(diff);
        lc += (ad < 1.0f) ? 0.5f * ad * ad : (ad - 0.5f);
      }
      spp += log1pf(expf(-fabsf(x))) + fmaxf(-x, 0.0f);  // softplus(-x)
    } else {
      spn += log1pf(expf(-fabsf(x))) + fmaxf(x, 0.0f);   // softplus(x)
    }
  }
#pragma unroll
  for (int off = 32; off >= 1; off >>= 1) {
    lc += __shfl_down(lc, off);
    spp += __shfl_down(spp, off);
    spn += __shfl_down(spn, off);
    np += __shfl_down(np, off);
  }
  if ((t & 63) == 0) {
    red[wave][0] = lc; red[wave][1] = spp; red[wave][2] = spn; red[wave][3] = np;
  }
  __syncthreads();
  if (t == 0) {
    float o0 = 0, o1 = 0, o2 = 0, o3 = 0;
#pragma unroll
    for (int w = 0; w < 8; w++) { o0 += red[w][0]; o1 += red[w][1]; o2 += red[w][2]; o3 += red[w][3]; }
    float* p = &partials[(size_t)blk * 8];
    __hip_atomic_store(&p[0], o0, __ATOMIC_RELAXED, __HIP_MEMORY_SCOPE_AGENT);
    __hip_atomic_store(&p[1], o1, __ATOMIC_RELAXED, __HIP_MEMORY_SCOPE_AGENT);
    __hip_atomic_store(&p[2], o2, __ATOMIC_RELAXED, __HIP_MEMORY_SCOPE_AGENT);
    __hip_atomic_store(&p[3], o3, __ATOMIC_RELAXED, __HIP_MEMORY_SCOPE_AGENT);
    __hip_atomic_store(&p[4], sub == 0 ? spg : 0.0f, __ATOMIC_RELAXED, __HIP_MEMORY_SCOPE_AGENT);
    __hip_atomic_store(&p[5], sub == 0 ? (float)sunm : 0.0f, __ATOMIC_RELAXED, __HIP_MEMORY_SCOPE_AGENT);
    __threadfence();
    int ticket = __hip_atomic_fetch_add(done, 1, __ATOMIC_ACQ_REL, __HIP_MEMORY_SCOPE_AGENT);
    s_last = (ticket == LF_BLOCKS - 1) ? 1 : 0;
  }
  __syncthreads();
  if (s_last) {
    __threadfence();
    float v[6] = {0, 0, 0, 0, 0, 0};
    if (t < LF_BLOCKS) {
#pragma unroll
      for (int q = 0; q < 6; q++)
        v[q] = __hip_atomic_load(&partials[(size_t)t * 8 + q], __ATOMIC_RELAXED, __HIP_MEMORY_SCOPE_AGENT);
    }
#pragma unroll
    for (int off = 32; off >= 1; off >>= 1) {
#pragma unroll
      for (int q = 0; q < 6; q++) v[q] += __shfl_down(v[q], off);
    }
    if (t < 128 && (t & 63) == 0) {
#pragma unroll
      for (int q = 0; q < 6; q++) red2[t >> 6][q] = v[q];
    }
    __syncthreads();
    if (t == 0) {
      float o0 = red2[0][0] + red2[1][0];
      float o1 = red2[0][1] + red2[1][1];
      float o2 = red2[0][2] + red2[1][2];
      float o3 = red2[0][3] + red2[1][3];
      float pg = red2[0][4] + red2[1][4];
      float ne = red2[0][5] + red2[1][5];
      float n_pos = o3;
      float loss_center = o0 / fmaxf(n_pos * 3.0f, 1.0f);
      float n_neg = (float)TOTAL - n_pos;
      float pw = fminf(10.0f, n_neg / fmaxf(n_pos, 1.0f));
      float loss_obj = (pw * o1 + o2) / (float)TOTAL;
      float loss_unm = pg / fmaxf(ne, 1.0f);
      out[0] = loss_center * wc[0] + loss_obj * wo[0] + loss_unm * wu[0];
    }
  }
}

extern "C" void kernel_launch(void* const* d_in, const int* in_sizes, int n_in,
                              void* d_out, int out_size, void* d_ws, size_t ws_size,
                              hipStream_t stream) {
  const float* pred_boxes = (const float*)d_in[0];
  // d_in[1] = pred_classes (unused), d_in[4] = gt_classes (unused), d_in[9] = epoch (unused)
  const float* pred_scores = (const float*)d_in[2];
  const float* gt_boxes = (const float*)d_in[3];
  const int* n_gt = (const int*)d_in[5];
  const float* wc = (const float*)d_in[6];
  const float* wo = (const float*)d_in[7];
  const float* wu = (const float*)d_in[8];
  float* out = (float*)d_out;

  char* ws = (char*)d_ws;
  float* packed = (float*)ws;                               // 3*TOTAL floats (3 MB)
  float* outd = (float*)(ws + (size_t)TOTAL * 12);          // NB*NS*NM*10 floats (64 KB)
  int* outi = (int*)((char*)outd + (size_t)NB * NS * NM * K10 * 4);  // 64 KB
  float* partials = (float*)((char*)outi + (size_t)NB * NS * NM * K10 * 4);  // 4 KB
  int* done = (int*)((char*)partials + LF_BLOCKS * 8 * 4 + 64);

  prep_kernel<<<512, 256, 0, stream>>>(pred_boxes, packed, done);
  topk_kernel<<<NB * NS * NM, TKT, 0, stream>>>(packed, gt_boxes, outd, outi);
  loss_final_kernel<<<LF_BLOCKS, LFT, 0, stream>>>(pred_boxes, pred_scores, gt_boxes, n_gt,
                                                   outd, outi, partials, done, wc, wo, wu, out);
}